// Round 1
// 423.120 us; speedup vs baseline: 1.0259x; 1.0259x over previous
//
#include <hip/hip_runtime.h>

#define FEATURES 1024
#define NREFL 4

typedef float f32x4 __attribute__((ext_vector_type(4)));

// Fused Householder apply: out = x * H0 * H1 * H2 * H3 (row-wise).
//
// Single kernel. Each 64-lane wave:
//   1. loads the 4 raw reflection vectors (16 KB, L2-hot after first block),
//      normalizes them in-register via 4 pipelined butterfly reductions
//      (redundant per wave, but removes the hh_normalize dispatch + the
//      graph dependency edge between the two kernels);
//   2. grid-strides over rows, 2 rows per iteration (two independent
//      shuffle-reduce chains, 2 KB of loads in flight per iteration).
// Lane l owns elements {c*256 + 4l .. +3} for c=0..3 — fully coalesced
// 1 KiB-per-instruction float4 access. x/out are streamed nontemporally
// (never re-read; keeps the L1/L2 allocate path clean).
__global__ __launch_bounds__(256) void hh_fused(const float* __restrict__ x,
                                                const float* __restrict__ vec,
                                                float* __restrict__ out,
                                                int batch) {
    const int lane   = threadIdx.x & 63;
    const int wave   = blockIdx.x * (blockDim.x >> 6) + (threadIdx.x >> 6);
    const int nwaves = gridDim.x * (blockDim.x >> 6);

    // ---- load + normalize all 4 reflection vectors into VGPRs ----
    f32x4 v[NREFL][4];
    float s[NREFL];
    #pragma unroll
    for (int i = 0; i < NREFL; ++i) {
        s[i] = 0.0f;
        #pragma unroll
        for (int c = 0; c < 4; ++c) {
            const f32x4 t = *(const f32x4*)(vec + i * FEATURES + c * 256 + lane * 4);
            v[i][c] = t;
            s[i] += t.x * t.x + t.y * t.y + t.z * t.z + t.w * t.w;
        }
    }
    // 4 independent 64-lane butterfly reductions, pipelined
    #pragma unroll
    for (int off = 32; off > 0; off >>= 1) {
        #pragma unroll
        for (int i = 0; i < NREFL; ++i) s[i] += __shfl_xor(s[i], off);
    }
    #pragma unroll
    for (int i = 0; i < NREFL; ++i) {
        const float inv = 1.0f / sqrtf(s[i]);   // keep full-precision (absmax margin)
        #pragma unroll
        for (int c = 0; c < 4; ++c) v[i][c] *= inv;
    }

    // ---- stream rows: 2 rows per iteration ----
    int row = wave;
    for (; row + nwaves < batch; row += 2 * nwaves) {
        const float* xr0 = x + (size_t)row * FEATURES;
        const float* xr1 = x + ((size_t)row + nwaves) * FEATURES;
        f32x4 ya[4], yb[4];
        #pragma unroll
        for (int c = 0; c < 4; ++c) {
            ya[c] = __builtin_nontemporal_load((const f32x4*)(xr0 + c * 256 + lane * 4));
            yb[c] = __builtin_nontemporal_load((const f32x4*)(xr1 + c * 256 + lane * 4));
        }

        #pragma unroll
        for (int i = 0; i < NREFL; ++i) {
            float da = 0.0f, db = 0.0f;
            #pragma unroll
            for (int c = 0; c < 4; ++c) {
                da += ya[c].x * v[i][c].x + ya[c].y * v[i][c].y +
                      ya[c].z * v[i][c].z + ya[c].w * v[i][c].w;
                db += yb[c].x * v[i][c].x + yb[c].y * v[i][c].y +
                      yb[c].z * v[i][c].z + yb[c].w * v[i][c].w;
            }
            #pragma unroll
            for (int off = 32; off > 0; off >>= 1) {
                da += __shfl_xor(da, off);
                db += __shfl_xor(db, off);
            }
            da *= 2.0f; db *= 2.0f;
            #pragma unroll
            for (int c = 0; c < 4; ++c) {
                ya[c] -= da * v[i][c];
                yb[c] -= db * v[i][c];
            }
        }

        float* o0 = out + (size_t)row * FEATURES;
        float* o1 = out + ((size_t)row + nwaves) * FEATURES;
        #pragma unroll
        for (int c = 0; c < 4; ++c) {
            __builtin_nontemporal_store(ya[c], (f32x4*)(o0 + c * 256 + lane * 4));
            __builtin_nontemporal_store(yb[c], (f32x4*)(o1 + c * 256 + lane * 4));
        }
    }
    // tail: single row (handles batch not divisible by 2*nwaves)
    for (; row < batch; row += nwaves) {
        const float* xr = x + (size_t)row * FEATURES;
        f32x4 y[4];
        #pragma unroll
        for (int c = 0; c < 4; ++c)
            y[c] = __builtin_nontemporal_load((const f32x4*)(xr + c * 256 + lane * 4));
        #pragma unroll
        for (int i = 0; i < NREFL; ++i) {
            float d = 0.0f;
            #pragma unroll
            for (int c = 0; c < 4; ++c)
                d += y[c].x * v[i][c].x + y[c].y * v[i][c].y +
                     y[c].z * v[i][c].z + y[c].w * v[i][c].w;
            #pragma unroll
            for (int off = 32; off > 0; off >>= 1) d += __shfl_xor(d, off);
            d *= 2.0f;
            #pragma unroll
            for (int c = 0; c < 4; ++c) y[c] -= d * v[i][c];
        }
        float* orow = out + (size_t)row * FEATURES;
        #pragma unroll
        for (int c = 0; c < 4; ++c)
            __builtin_nontemporal_store(y[c], (f32x4*)(orow + c * 256 + lane * 4));
    }
}

extern "C" void kernel_launch(void* const* d_in, const int* in_sizes, int n_in,
                              void* d_out, int out_size, void* d_ws, size_t ws_size,
                              hipStream_t stream) {
    const float* x   = (const float*)d_in[0];
    const float* vec = (const float*)d_in[1];
    float* out = (float*)d_out;

    const int batch = in_sizes[0] / FEATURES;

    // 2048 blocks * 4 waves = 8192 waves; each wave handles batch/8192 = 8 rows
    // (4 iterations of 2 rows). ~116 VGPRs -> 4 waves/SIMD resident, far more
    // than the ~10 KB/CU of in-flight traffic needed to saturate HBM.
    hh_fused<<<2048, 256, 0, stream>>>(x, vec, out, batch);
}